// Round 1
// baseline (231.937 us; speedup 1.0000x reference)
//
#include <hip/hip_runtime.h>
#include <stdint.h>
#include <math.h>

// SineKANLayer: y[b,o] = sum_{j,d} sin(x[b,j]*freq[d] + (gp[d]+ip[j])*R) * amp[o,j,d] + bias[o]
// == GEMM  S(BxK) @ amp^T(KxO), K = IN*G, k = j*G + d  (amp is (O,K) row-major already)
//
// Strategy: amp pre-cast fp32->bf16 (RNE) into d_ws; fused GEMM computes the
// sine A-fragments in registers (A needs NO LDS: the 8 contiguous k of an
// mfma_f32_16x16x32_bf16 A-frag are exactly d=0..7 of one j since G=8).
// B staged via global_load_lds(16B). BM=64,BN=128,BK=64, 256 thr, 2x2 waves.

#define BM 64
#define BN 128
#define BK 64

typedef unsigned short u16;
typedef __attribute__((ext_vector_type(8))) short bf16x8;   // 8 bf16 = 4 VGPRs
typedef __attribute__((ext_vector_type(4))) float f32x4;    // mfma acc

__device__ inline void load_lds16(const void* g, void* l) {
  __builtin_amdgcn_global_load_lds(
      (const __attribute__((address_space(1))) void*)g,
      (__attribute__((address_space(3))) void*)l, 16, 0, 0);
}

__device__ inline u16 bf16_rne(float f) {
  uint32_t u = __builtin_bit_cast(uint32_t, f);
  u += 0x7fffu + ((u >> 16) & 1u);
  return (u16)(u >> 16);
}

__global__ void cast_amp(const float* __restrict__ a, u16* __restrict__ o, int n) {
  int i = (blockIdx.x * 256 + threadIdx.x) * 4;
  if (i + 3 < n) {
    float4 v = *(const float4*)(a + i);
    ushort4 r;
    r.x = bf16_rne(v.x); r.y = bf16_rne(v.y);
    r.z = bf16_rne(v.z); r.w = bf16_rne(v.w);
    *(ushort4*)(o + i) = r;
  } else {
    for (int t = i; t < n; ++t) o[t] = bf16_rne(a[t]);
  }
}

__launch_bounds__(256, 2)
__global__ void sinekan_gemm(const float* __restrict__ x,
                             const u16* __restrict__ ampb,   // (O, K) bf16 row-major
                             const float* __restrict__ freq, // G floats
                             const float* __restrict__ bias, // O floats
                             float* __restrict__ out,        // (B, O) fp32
                             int IN, int O, int K,
                             float R, float ipstep)          // ipstep = pi/(IN-1)
{
  const int tid = threadIdx.x;
  const int l   = tid & 63;
  const int w   = tid >> 6;
  const int wr  = w & 1;      // wave row (M dir), 0..1 -> 32 rows each
  const int wc  = w >> 1;     // wave col (N dir), 0..1 -> 64 cols each
  const int q   = l >> 4;     // quad 0..3
  const int lm  = l & 15;

  const int bn = blockIdx.x;  // N tile
  const int bm = blockIdx.y;  // M tile

  __shared__ u16   Bs[BN * BK];   // [n][k] 128x64 bf16, 16 KB (no pad: global_load_lds)
  __shared__ float xs[8 * 72];    // [j_local][row], stride 72 (72%32==8 -> 2-way only)

  const float inv2pi = 0.15915494309189535f;
  float F[8], P[8];
#pragma unroll
  for (int d = 0; d < 8; ++d) {
    F[d] = freq[d] * inv2pi;                         // x coefficient (revolutions)
    P[d] = ((float)(d + 1) / 9.0f) * R * inv2pi;     // grid-phase part
  }
  const float cJ = ipstep * R * inv2pi;              // per-j phase step

  f32x4 acc[2][4] = {};   // [mt][nt], wave-tile 32x64

  const int nK = K / BK;
  for (int t = 0; t < nK; ++t) {
    const int kb = t * BK;
    const int jb = kb >> 3;   // 8 j-columns per K-tile

    // ---- stage B tile: 128 rows x 64 k (bf16), 16B/lane direct-to-LDS ----
#pragma unroll
    for (int it = 0; it < 4; ++it) {
      int flat = tid + it * 256;              // 0..1023
      int row = flat >> 3, seg = flat & 7;
      const u16* gp = ampb + (size_t)(bn * BN + row) * K + kb + seg * 8;
      load_lds16((const void*)gp, (void*)(Bs + flat * 8));
    }
    // ---- stage x tile: 64 rows x 8 j, transposed into xs[j][row] ----
    if (tid < 128) {
      int row = tid >> 1, jh = tid & 1;
      const float* xp = x + (size_t)(bm * BM + row) * IN + jb + jh * 4;
      float4 v = *(const float4*)xp;
      xs[(jh * 4 + 0) * 72 + row] = v.x;
      xs[(jh * 4 + 1) * 72 + row] = v.y;
      xs[(jh * 4 + 2) * 72 + row] = v.z;
      xs[(jh * 4 + 3) * 72 + row] = v.w;
    }
    __syncthreads();

#pragma unroll
    for (int ks = 0; ks < 2; ++ks) {
      const int jl = ks * 4 + q;                       // this lane's j within tile
      const float cb = (float)(jb + jl) * cJ;
      float AD[8];
#pragma unroll
      for (int d = 0; d < 8; ++d) AD[d] = P[d] + cb;   // full phase (revolutions)

      // A fragments computed in registers: row = wr*32 + mt*16 + lm, k = jl*8 + d
      bf16x8 af[2];
#pragma unroll
      for (int mt = 0; mt < 2; ++mt) {
        const float xv = xs[jl * 72 + (wr * 32 + mt * 16 + lm)];
        float s[8];
#pragma unroll
        for (int d = 0; d < 8; ++d)
          s[d] = __builtin_amdgcn_sinf(__builtin_fmaf(xv, F[d], AD[d]));
        union { bf16x8 v; uint32_t u[4]; } fa;
#pragma unroll
        for (int p2 = 0; p2 < 4; ++p2) {
          uint32_t lo = __builtin_bit_cast(uint32_t, s[2 * p2]);
          uint32_t hi = __builtin_bit_cast(uint32_t, s[2 * p2 + 1]);
          fa.u[p2] = __builtin_amdgcn_perm(hi, lo, 0x07060302);  // pack 2x bf16 (RTZ)
        }
        af[mt] = fa.v;
      }

      // B fragments from LDS: n = wc*64 + nt*16 + lm, k = ks*32 + q*8
      bf16x8 bfr[4];
#pragma unroll
      for (int nt = 0; nt < 4; ++nt) {
        const u16* bp = Bs + (wc * 64 + nt * 16 + lm) * BK + ks * 32 + q * 8;
        bfr[nt] = *(const bf16x8*)bp;
      }

#pragma unroll
      for (int mt = 0; mt < 2; ++mt)
#pragma unroll
        for (int nt = 0; nt < 4; ++nt)
          acc[mt][nt] = __builtin_amdgcn_mfma_f32_16x16x32_bf16(
              af[mt], bfr[nt], acc[mt][nt], 0, 0, 0);
    }
    __syncthreads();
  }

  // ---- epilogue: C/D layout col=lane&15, row=(lane>>4)*4+reg ----
#pragma unroll
  for (int nt = 0; nt < 4; ++nt) {
    const int n = bn * BN + wc * 64 + nt * 16 + lm;
    const float bv = bias[n];
#pragma unroll
    for (int mt = 0; mt < 2; ++mt) {
      const int mbase = bm * BM + wr * 32 + mt * 16 + q * 4;
#pragma unroll
      for (int r = 0; r < 4; ++r)
        out[(size_t)(mbase + r) * O + n] = acc[mt][nt][r] + bv;
    }
  }
}

extern "C" void kernel_launch(void* const* d_in, const int* in_sizes, int n_in,
                              void* d_out, int out_size, void* d_ws, size_t ws_size,
                              hipStream_t stream) {
  const float* x    = (const float*)d_in[0];
  const float* amp  = (const float*)d_in[1];
  const float* freq = (const float*)d_in[2];
  const float* bias = (const float*)d_in[3];
  float* out = (float*)d_out;

  const int ampN = in_sizes[1];          // O*IN*G
  const int G    = in_sizes[2];          // 8
  const int O    = in_sizes[3];          // 512
  const int IN   = ampN / (O * G);       // 1024
  const int B    = in_sizes[0] / IN;     // 8192
  const int K    = IN * G;               // 8192

  u16* ampb = (u16*)d_ws;                // needs O*K*2 = 8.4 MB of scratch

  int nb = (ampN + 1023) / 1024;
  cast_amp<<<nb, 256, 0, stream>>>(amp, ampb, ampN);

  const double ratio = 0.9724 * pow((double)G, -0.9884) + 0.9994;
  const float R = (float)pow(ratio, (double)(G - 1));
  const float ipstep = (float)(M_PI / (double)(IN - 1));

  dim3 grid(O / BN, B / BM);
  sinekan_gemm<<<grid, 256, 0, stream>>>(x, ampb, freq, bias, out, IN, O, K, R, ipstep);
}

// Round 2
// 190.719 us; speedup vs baseline: 1.2161x; 1.2161x over previous
//
#include <hip/hip_runtime.h>
#include <stdint.h>
#include <math.h>

// SineKANLayer: y[b,o] = sum_{j,d} sin(x[b,j]*freq[d] + ((d+1)/9 + j*ipstep)*R) * amp[o,j,d] + bias[o]
// == GEMM S(BxK) @ amp^T(KxO), K=IN*G, k=j*8+d. amp is (O,K) row-major (gemm_bt form).
//
// R2 changes vs R1:
//  - XOR-swizzled B layout in LDS (seg ^ (row&7)) applied on the global_load_lds
//    SOURCE address (LDS side must stay lane-contiguous) -> 16-way bank conflict -> 2-way (free).
//  - Chebyshev: angle_d = (d+1)*t + j*c is an arithmetic progression -> 3 transcendentals
//    + 6 FMA instead of 8 sins per 8-elem A-fragment.
//  - Wave-tile 64x128 (mt=4,nt=8): halves LDS B-read traffic (prop. 1/M_wave) and halves
//    sine duplication (O/N_wave = 4x).
//  - Split-K=4 with f32 atomicAdd epilogue (out pre-initialized to bias by prelude kernel)
//    to get 2048 waves (2/SIMD) instead of 512 (0.5/SIMD).

#define BM 128
#define BN 128
#define BK 64
#define SK 4

typedef unsigned short u16;
typedef __attribute__((ext_vector_type(8))) short bf16x8;   // 8 bf16 = 4 VGPRs
typedef __attribute__((ext_vector_type(4))) float f32x4;

__device__ inline void load_lds16(const void* g, void* l) {
  __builtin_amdgcn_global_load_lds(
      (const __attribute__((address_space(1))) void*)g,
      (__attribute__((address_space(3))) void*)l, 16, 0, 0);
}

__device__ inline u16 bf16_rne(float f) {
  uint32_t u = __builtin_bit_cast(uint32_t, f);
  u += 0x7fffu + ((u >> 16) & 1u);
  return (u16)(u >> 16);
}

// fused prelude: (a) cast amp fp32->bf16 into ws, (b) out = bias (split-K accumulates on top)
__global__ void prelude(const float* __restrict__ amp, u16* __restrict__ ampb, int ampN4,
                        const float* __restrict__ bias, float* __restrict__ out, int outN4,
                        int O4m1) {
  int i = blockIdx.x * 256 + threadIdx.x;
  if (i < ampN4) {
    float4 v = ((const float4*)amp)[i];
    ushort4 r;
    r.x = bf16_rne(v.x); r.y = bf16_rne(v.y);
    r.z = bf16_rne(v.z); r.w = bf16_rne(v.w);
    ((ushort4*)ampb)[i] = r;
  } else {
    int j = i - ampN4;
    if (j < outN4) ((float4*)out)[j] = ((const float4*)bias)[j & O4m1];
  }
}

__launch_bounds__(128, 2)
__global__ void sinekan_gemm(const float* __restrict__ x,
                             const u16* __restrict__ ampb,   // (O,K) bf16 row-major
                             const float* __restrict__ freq, // only freq[0] needed
                             float* __restrict__ out,        // (B,O) f32, pre-init to bias
                             int IN, int O, int K,
                             float R, float cJ)              // cJ = ipstep*R/(2pi)
{
  const int tid = threadIdx.x;
  const int l   = tid & 63;
  const int w   = tid >> 6;     // wave M position: rows w*64..w*64+63
  const int q   = l >> 4;
  const int lm  = l & 15;

  const int bn = blockIdx.x;
  const int bm = blockIdx.y;
  const int sk = blockIdx.z;

  __shared__ u16   Bs[BN * BK];   // [n][seg^(n&7)] swizzled, 16 KB
  __shared__ float xs[8 * 136];   // [j][row], stride 136 (banks +8/j -> <=2-way)

  const float inv2pi = 0.15915494309189535f;
  const float F1 = freq[0] * inv2pi;   // (1/9)/2pi : t-step per (d+1)
  const float P1 = F1 * R;             // t = x*F1 + P1  (the (d+1)-proportional phase)

  f32x4 acc[4][8] = {};   // wave-tile 64x128

  const int KC    = K / SK;
  const int kb0   = sk * KC;
  const int iters = KC / BK;

  for (int t = 0; t < iters; ++t) {
    const int kb = kb0 + t * BK;
    const int jb = kb >> 3;

    // ---- stage B tile 128n x 64k bf16: 1024 16B segs, 8 per thread, swizzled source ----
#pragma unroll
    for (int it = 0; it < 8; ++it) {
      int flat = tid + it * 128;
      int row = flat >> 3, seg = flat & 7;
      int sg = seg ^ (row & 7);
      const u16* gp = ampb + (size_t)(bn * BN + row) * K + kb + sg * 8;
      load_lds16((const void*)gp, (void*)(Bs + flat * 8));
    }
    // ---- stage x tile: 128 rows x 8 j, transposed ----
#pragma unroll
    for (int it = 0; it < 2; ++it) {
      int flat = tid + it * 128;
      int row = flat >> 1, jh = flat & 1;
      const float* xp = x + (size_t)(bm * BM + row) * IN + jb + jh * 4;
      float4 v = *(const float4*)xp;
      xs[(jh * 4 + 0) * 136 + row] = v.x;
      xs[(jh * 4 + 1) * 136 + row] = v.y;
      xs[(jh * 4 + 2) * 136 + row] = v.z;
      xs[(jh * 4 + 3) * 136 + row] = v.w;
    }
    __syncthreads();

#pragma unroll
    for (int ks = 0; ks < 2; ++ks) {
      const int jl = ks * 4 + q;
      const float c = (float)(jb + jl) * cJ;

      // A fragments in registers via Chebyshev recurrence:
      // s_d = sin(c + (d+1)t),  s_d = 2cos(t)*s_{d-1} - s_{d-2}
      bf16x8 af[4];
#pragma unroll
      for (int mt = 0; mt < 4; ++mt) {
        const float xv = xs[jl * 136 + (w * 64 + mt * 16 + lm)];
        const float tt = __builtin_fmaf(xv, F1, P1);
        const float ct = __builtin_amdgcn_cosf(tt);
        const float k2 = ct + ct;
        float s[8];
        s[0] = __builtin_amdgcn_sinf(c + tt);
        s[1] = __builtin_amdgcn_sinf(__builtin_fmaf(2.0f, tt, c));
#pragma unroll
        for (int d = 2; d < 8; ++d)
          s[d] = __builtin_fmaf(k2, s[d - 1], -s[d - 2]);
        union { bf16x8 v; uint32_t u[4]; } fa;
#pragma unroll
        for (int p2 = 0; p2 < 4; ++p2) {
          uint32_t lo = __builtin_bit_cast(uint32_t, s[2 * p2]);
          uint32_t hi = __builtin_bit_cast(uint32_t, s[2 * p2 + 1]);
          fa.u[p2] = __builtin_amdgcn_perm(hi, lo, 0x07060302);
        }
        af[mt] = fa.v;
      }

      // B fragments: n = nt*16+lm, logical seg = ks*4+q, stored at seg^(n&7)
      bf16x8 bfr[8];
#pragma unroll
      for (int nt = 0; nt < 8; ++nt) {
        int n = nt * 16 + lm;
        int sl = (ks * 4 + q) ^ (lm & 7);
        const u16* bp = Bs + n * 64 + sl * 8;
        bfr[nt] = *(const bf16x8*)bp;
      }

#pragma unroll
      for (int mt = 0; mt < 4; ++mt)
#pragma unroll
        for (int nt = 0; nt < 8; ++nt)
          acc[mt][nt] = __builtin_amdgcn_mfma_f32_16x16x32_bf16(
              af[mt], bfr[nt], acc[mt][nt], 0, 0, 0);
    }
    __syncthreads();
  }

  // ---- epilogue: split-K accumulate. C/D layout col=lane&15, row=q*4+r ----
#pragma unroll
  for (int nt = 0; nt < 8; ++nt) {
    const int n = bn * BN + nt * 16 + lm;
#pragma unroll
    for (int mt = 0; mt < 4; ++mt) {
      const int mbase = bm * BM + w * 64 + mt * 16 + q * 4;
#pragma unroll
      for (int r = 0; r < 4; ++r)
        atomicAdd(out + (size_t)(mbase + r) * O + n, acc[mt][nt][r]);
    }
  }
}

extern "C" void kernel_launch(void* const* d_in, const int* in_sizes, int n_in,
                              void* d_out, int out_size, void* d_ws, size_t ws_size,
                              hipStream_t stream) {
  const float* x    = (const float*)d_in[0];
  const float* amp  = (const float*)d_in[1];
  const float* freq = (const float*)d_in[2];
  const float* bias = (const float*)d_in[3];
  float* out = (float*)d_out;

  const int ampN = in_sizes[1];          // O*IN*G
  const int G    = in_sizes[2];          // 8
  const int O    = in_sizes[3];          // 512
  const int IN   = ampN / (O * G);       // 1024
  const int B    = in_sizes[0] / IN;     // 8192
  const int K    = IN * G;               // 8192

  u16* ampb = (u16*)d_ws;                // O*K*2 = 8.4 MB scratch

  const int ampN4 = ampN / 4;
  const int outN4 = out_size / 4;
  const int O4m1  = O / 4 - 1;
  int nb = (ampN4 + outN4 + 255) / 256;
  prelude<<<nb, 256, 0, stream>>>(amp, ampb, ampN4, bias, out, outN4, O4m1);

  const double ratio = 0.9724 * pow((double)G, -0.9884) + 0.9994;
  const float R = (float)pow(ratio, (double)(G - 1));
  const float ipstep = (float)(M_PI / (double)(IN - 1));
  const float cJ = ipstep * R * 0.15915494309189535f;

  dim3 grid(O / BN, B / BM, SK);
  sinekan_gemm<<<grid, 128, 0, stream>>>(x, ampb, freq, out, IN, O, K, R, cJ);
}